// Round 5
// baseline (21.488 us; speedup 1.0000x reference)
//
#include <hip/hip_runtime.h>

#define BATCH 128
#define DVAR  64
#define HDIM  128
#define NT    512    // 8 waves/block, 2 blocks/CU (LDS ~68.5 KB/block)

typedef __attribute__((ext_vector_type(8))) __bf16 bf16x8;
typedef __attribute__((ext_vector_type(4))) float  f32x4;

__device__ __forceinline__ unsigned short f2bf(float f) {
    unsigned u = __float_as_uint(f);
    u += 0x7FFF + ((u >> 16) & 1);          // round-to-nearest-even
    return (unsigned short)(u >> 16);
}

// tanh(x) = 1 - 2/(e^{2x}+1); v_exp_f32 + v_rcp_f32, ~6 inst, err ~1e-5 << bf16 quant
__device__ __forceinline__ float fast_tanh(float x) {
    const float e = __expf(2.0f * x);       // inf for large x -> rcp=0 -> 1; 0 for small -> -1
    return fmaf(-2.0f, __builtin_amdgcn_rcpf(e + 1.0f), 1.0f);
}

// ---------------- pre-pack: fp32 weights -> bf16 B-fragments in d_ws ----------------
// B-frag layout for mfma_f32_16x16x32_bf16: lane l supplies B[k=(l>>4)*8+e][col=l&15].
// sections: mw1 (K=256, KB=8) at 0; mw2 (K=128, KB=4) at 32768; dw1 (K=256, KB=8) at 49152.
__global__ void pack_w(const float* __restrict__ mw1, const float* __restrict__ mw2,
                       const float* __restrict__ dw1, unsigned short* __restrict__ ws) {
    int t = blockIdx.x * 256 + threadIdx.x;          // 0..10239
    const float* src; unsigned short* dst; int KB;
    if (t < 4096)      { src = mw1; dst = ws;         KB = 8; }
    else if (t < 6144) { src = mw2; dst = ws + 32768; KB = 4; t -= 4096; }
    else               { src = dw1; dst = ws + 49152; KB = 8; t -= 6144; }
    const int l  = t & 63, g = t >> 6;
    const int kb = g % KB, n = g / KB;
    const int k0  = kb * 32 + (l >> 4) * 8;
    const int col = n * 16 + (l & 15);
    unsigned short o[8];
    #pragma unroll
    for (int e = 0; e < 8; ++e) o[e] = f2bf(src[(k0 + e) * HDIM + col]);
    uint4 pk;
    unsigned short* pp = (unsigned short*)&pk;
    #pragma unroll
    for (int e = 0; e < 8; ++e) pp[e] = o[e];
    *(uint4*)(dst + (size_t)t * 8) = pk;             // coalesced 16B store
}

// ---------------- main fused kernel ----------------
// Grid 512 = (b = blockIdx>>2, i0 = (blockIdx&3)*16), 512 threads = 8 waves.
__global__ __launch_bounds__(NT, 4) void gnn_fused(
    const float* __restrict__ X,  const float* __restrict__ W,
    const float* __restrict__ enc_w, const float* __restrict__ enc_b,
    const float* __restrict__ mb1, const float* __restrict__ mb2,
    const float* __restrict__ db1, const float* __restrict__ dw2,
    const float* __restrict__ db2,
    const unsigned short* __restrict__ ws,   // packed bf16 weights
    float* __restrict__ out)
{
    __shared__ unsigned short h_bf[DVAR * HDIM];   // 16 KB, XOR-swizzled rows
    __shared__ float          u_lds[DVAR * HDIM];  // 32 KB; rows 0..15 reused as z
    __shared__ float          v_lds[16 * HDIM];    // 8 KB
    __shared__ float          A_lds[DVAR][16];     // 4 KB
    __shared__ unsigned short r_bf[16 * HDIM];     // 4 KB, swizzled
    __shared__ unsigned short agg_bf[16 * HDIM];   // 4 KB, swizzled
    __shared__ float          Asum[16];

    const int tid  = threadIdx.x;
    const int b    = blockIdx.x >> 2;
    const int i0   = (blockIdx.x & 3) * 16;        // this block's i range [i0, i0+16)
    const int k    = tid & (HDIM - 1);
    const int g    = tid >> 7;          // 0..3, wave-uniform (g = w>>1)
    const int w    = tid >> 6;          // wave 0..7
    const int lane = tid & 63;
    const int lrow = lane & 15;
    const int lhi  = lane >> 4;

    const bf16x8* mw1p = (const bf16x8*)(const void*)(ws);
    const bf16x8* mw2p = (const bf16x8*)(const void*)(ws + 32768);
    const bf16x8* dw1p = (const bf16x8*)(const void*)(ws + 49152);

    // ---- P1: h = tanh(X*enc_w+enc_b) -> bf16 LDS (swizzled); stage A slab ----
    {
        const float ew = enc_w[k];
        const float eb = enc_b[k];
        #pragma unroll
        for (int m = 0; m < 16; ++m) {
            const int j = g + m * 4;                       // wave-uniform row
            h_bf[(j * HDIM + k) ^ ((j & 7) << 3)] = f2bf(fast_tanh(X[b * DVAR + j] * ew + eb));
        }
        #pragma unroll
        for (int m = 0; m < 2; ++m) {
            const int idx = tid + m * NT;                  // 0..1023
            const int j = idx >> 4, ii = idx & 15;
            A_lds[j][ii] = (j == i0 + ii) ? 0.0f : W[j * DVAR + i0 + ii];
        }
    }
    __syncthreads();
    if (tid < 16) {                                        // Asum[ii] = sum_j A[j,i]
        float s = 0.0f;
        for (int j = 0; j < DVAR; ++j) s += A_lds[j][tid];
        Asum[tid] = s;
    }

    // ---- P2 (MFMA): u[64][128] = h @ mw1[:H]; v[16][128] = h[i0:i0+16] @ mw1[H:] ----
    // 40 tiles (32 u + 8 v) over 8 waves = 5 tiles/wave.
    #pragma unroll
    for (int tt = 0; tt < 5; ++tt) {
        const int id = w + tt * 8;                         // 0..39
        const bool isU = id < 32;
        const int rt = isU ? (id >> 3) : 0;
        const int ct = isU ? (id & 7) : (id - 32);
        const int row = (isU ? rt * 16 : i0) + lrow;       // A-operand source row
        const int kbB0 = isU ? 0 : 4;
        f32x4 acc = {0.f, 0.f, 0.f, 0.f};
        #pragma unroll
        for (int kb = 0; kb < 4; ++kb) {
            const int eidx = (row * HDIM + kb * 32 + lhi * 8) ^ ((row & 7) << 3);
            bf16x8 a = *(const bf16x8*)(const void*)(h_bf + eidx);
            bf16x8 bb = mw1p[(ct * 8 + kbB0 + kb) * 64 + lane];
            acc = __builtin_amdgcn_mfma_f32_16x16x32_bf16(a, bb, acc, 0, 0, 0);
        }
        float* dst = isU ? u_lds : v_lds;
        const int orow0 = rt * 16 + lhi * 4;
        const int col = ct * 16 + lrow;
        #pragma unroll
        for (int r = 0; r < 4; ++r) dst[(orow0 + r) * HDIM + col] = acc[r];
    }
    __syncthreads();

    // ---- P3 (VALU): r[ii][k] = sum_j A[j][ii] * relu(u[j][k] + v[ii][k] + mb1[k]) ----
    {
        const float bk = mb1[k];
        float vvv[4];
        #pragma unroll
        for (int ii = 0; ii < 4; ++ii) vvv[ii] = v_lds[(g * 4 + ii) * HDIM + k] + bk;
        float racc[4] = {0.f, 0.f, 0.f, 0.f};
        #pragma unroll 4
        for (int j = 0; j < DVAR; ++j) {
            const float uv = u_lds[j * HDIM + k];
            const float4 a4 = *(const float4*)&A_lds[j][g * 4];   // wave-broadcast
            racc[0] = fmaf(fmaxf(uv + vvv[0], 0.f), a4.x, racc[0]);
            racc[1] = fmaf(fmaxf(uv + vvv[1], 0.f), a4.y, racc[1]);
            racc[2] = fmaf(fmaxf(uv + vvv[2], 0.f), a4.z, racc[2]);
            racc[3] = fmaf(fmaxf(uv + vvv[3], 0.f), a4.w, racc[3]);
        }
        #pragma unroll
        for (int ii = 0; ii < 4; ++ii) {
            const int row = g * 4 + ii;
            r_bf[(row * HDIM + k) ^ ((row & 7) << 3)] = f2bf(racc[ii]);
        }
    }
    __syncthreads();

    // ---- P4 (MFMA): agg[16][128] = r @ mw2 + Asum*mb2 -> bf16 LDS (swizzled) ----
    {
        f32x4 acc = {0.f, 0.f, 0.f, 0.f};
        #pragma unroll
        for (int kb = 0; kb < 4; ++kb) {
            const int eidx = (lrow * HDIM + kb * 32 + lhi * 8) ^ ((lrow & 7) << 3);
            bf16x8 a = *(const bf16x8*)(const void*)(r_bf + eidx);
            bf16x8 bb = mw2p[(w * 4 + kb) * 64 + lane];
            acc = __builtin_amdgcn_mfma_f32_16x16x32_bf16(a, bb, acc, 0, 0, 0);
        }
        const int col = w * 16 + lrow;
        const float m2 = mb2[col];
        #pragma unroll
        for (int r = 0; r < 4; ++r) {
            const int row = lhi * 4 + r;
            const float val = acc[r] + Asum[row] * m2;
            agg_bf[(row * HDIM + col) ^ ((row & 7) << 3)] = f2bf(val);
        }
    }
    __syncthreads();

    // ---- P5 (MFMA): z = relu(h[i0:]@dw1[:H] + agg@dw1[H:] + db1) -> u_lds rows 0..15 ----
    {
        f32x4 acc = {0.f, 0.f, 0.f, 0.f};
        #pragma unroll
        for (int kb = 0; kb < 4; ++kb) {
            const int row = i0 + lrow;
            const int eidx = (row * HDIM + kb * 32 + lhi * 8) ^ ((row & 7) << 3);
            bf16x8 a = *(const bf16x8*)(const void*)(h_bf + eidx);
            bf16x8 bb = dw1p[(w * 8 + kb) * 64 + lane];
            acc = __builtin_amdgcn_mfma_f32_16x16x32_bf16(a, bb, acc, 0, 0, 0);
        }
        #pragma unroll
        for (int kb = 0; kb < 4; ++kb) {
            const int eidx = (lrow * HDIM + kb * 32 + lhi * 8) ^ ((lrow & 7) << 3);
            bf16x8 a = *(const bf16x8*)(const void*)(agg_bf + eidx);
            bf16x8 bb = dw1p[(w * 8 + 4 + kb) * 64 + lane];
            acc = __builtin_amdgcn_mfma_f32_16x16x32_bf16(a, bb, acc, 0, 0, 0);
        }
        const int col = w * 16 + lrow;
        const float db = db1[col];
        #pragma unroll
        for (int r = 0; r < 4; ++r)
            u_lds[(lhi * 4 + r) * HDIM + col] = fmaxf(acc[r] + db, 0.f);   // z
    }
    __syncthreads();

    // ---- P6: out[b][i0+row] = z[row] @ dw2 + db2 ----
    {
        const int row = tid >> 5;      // 0..15
        const int s   = tid & 31;
        float part = 0.0f;
        #pragma unroll
        for (int m = 0; m < 4; ++m) {
            const int kk = s + m * 32;
            part += u_lds[row * HDIM + kk] * dw2[kk];
        }
        part += __shfl_xor(part, 1);
        part += __shfl_xor(part, 2);
        part += __shfl_xor(part, 4);
        part += __shfl_xor(part, 8);
        part += __shfl_xor(part, 16);
        if (s == 0) out[b * DVAR + i0 + row] = part + db2[0];
    }
}

extern "C" void kernel_launch(void* const* d_in, const int* in_sizes, int n_in,
                              void* d_out, int out_size, void* d_ws, size_t ws_size,
                              hipStream_t stream) {
    const float* X     = (const float*)d_in[0];
    const float* W     = (const float*)d_in[1];
    const float* enc_w = (const float*)d_in[2];
    const float* enc_b = (const float*)d_in[3];
    const float* mw1   = (const float*)d_in[4];
    const float* mb1   = (const float*)d_in[5];
    const float* mw2   = (const float*)d_in[6];
    const float* mb2   = (const float*)d_in[7];
    const float* dw1   = (const float*)d_in[8];
    const float* db1   = (const float*)d_in[9];
    const float* dw2   = (const float*)d_in[10];
    const float* db2   = (const float*)d_in[11];
    unsigned short* wsp = (unsigned short*)d_ws;

    pack_w<<<dim3(40), dim3(256), 0, stream>>>(mw1, mw2, dw1, wsp);
    gnn_fused<<<dim3(BATCH * 4), dim3(NT), 0, stream>>>(
        X, W, enc_w, enc_b, mb1, mb2, db1, dw2, db2, wsp, (float*)d_out);
}